// Round 20
// baseline (137.757 us; speedup 1.0000x reference)
//
#include <hip/hip_runtime.h>
#include <hip/hip_bf16.h>

#define FHH 64
#define FWW 64
#define CIN 256
#define NB 4
#define NA 9
#define NANCH 36864
#define NPOS 4096
#define OC_TOTAL 45
#define OCP 48
#define MAXROIS 32
#define ROI 7
#define NEGV -1e30f
#define NCHUNK 576
#define NTH 16
#define CAP 1024

typedef unsigned long long u64;

__device__ __constant__ const float TH_LADDER[NTH] = {
    0.9999f, 0.9998f, 0.9995f, 0.999f, 0.998f, 0.997f, 0.995f, 0.993f,
    0.99f, 0.987f, 0.984f, 0.98f, 0.975f, 0.97f, 0.96f, 0.0f};

// choose deepest ladder index with cumulative count <= cap (gcnt = per-bucket counts)
__device__ __forceinline__ void pick_threshold2(
    const int* __restrict__ gcnt, int b, int cap,
    int* isel, int* C, int* V, int* frc)
{
    int cum = 0, bestC = 0, best_i = -1;
#pragma unroll
    for (int i = 0; i < NTH; ++i) {
        cum += gcnt[b * NTH + i];
        if (cum <= cap && cum > bestC) { bestC = cum; best_i = i; }
    }
    int f = (gcnt[b * NTH + 0] > cap) ? 1 : 0;
    if (f) { bestC = cap; best_i = 0; }
    *isel = best_i; *C = bestC; *V = cum; *frc = f;
}

// ---------------- Weight transpose + gcnt zero: wT[256][9][48] ----------------
__global__ __launch_bounds__(256) void wtrans_kernel(
    const float* __restrict__ wcls,
    const float* __restrict__ wloc,
    float* __restrict__ wT,
    int* __restrict__ gcnt)
{
    if (blockIdx.x == 0 && threadIdx.x < NB * NTH) gcnt[threadIdx.x] = 0;
    int idx = blockIdx.x * 256 + threadIdx.x;   // 110592 = 256*9*48
    int o = idx % 48;
    int rest = idx / 48;
    int tap = rest % 9;
    int c = rest / 9;
    float v = 0.f;
    if (o < OC_TOTAL) {
        v = (o < NA) ? wcls[((size_t)o * CIN + c) * 9 + tap]
                     : wloc[((size_t)(o - NA) * CIN + c) * 9 + tap];
    }
    wT[idx] = v;
}

// ---------------- Conv v10: 16x8 tile, 2x1 pos x 12 oc; 2048 blocks (8/CU) ----------------
__global__ __launch_bounds__(256) void conv_kernel(
    const float* __restrict__ feat,
    const float* __restrict__ wT,      // [256][9][48]
    float* __restrict__ partial,       // [nkg][4][48][4096]
    int nkg, int cpk)
{
    __shared__ float flds[16][18][12];   // 13824 B

    int blk = blockIdx.x;
    int low = blk & 7;
    int rest = blk >> 3;
    int kg = rest % nkg;
    int uhi = rest / nkg;          // 0..15
    int unit = uhi * 8 + low;      // 0..127
    int b = unit >> 5;
    int tile = unit & 31;
    int ty0 = (tile >> 3) * 16;    // 0,16,32,48
    int tx0 = (tile & 7) * 8;      // 0..56

    int pb = threadIdx.x & 63;
    int q = __builtin_amdgcn_readfirstlane(threadIdx.x >> 6);
    int ry0 = (pb >> 3) * 2;       // 0..14
    int rx0 = pb & 7;              // 0..7

    int cbase = kg * cpk;

    float acc[2][12];
#pragma unroll
    for (int py = 0; py < 2; ++py)
#pragma unroll
        for (int o = 0; o < 12; ++o) acc[py][o] = 0.f;

    for (int c0 = 0; c0 < cpk; c0 += 16) {
        __syncthreads();
        // stage 16 ch x 18 rows x 10 cols
        for (int idx = threadIdx.x; idx < 16 * 180; idx += 256) {
            int c = idx / 180;
            int r = idx - c * 180;
            int y = r / 10;
            int x = r - y * 10;
            int gy = ty0 + y - 1;
            int gx = tx0 + x - 1;
            float v = 0.f;
            if ((unsigned)gy < FHH && (unsigned)gx < FWW)
                v = feat[((size_t)(b * CIN + cbase + c0 + c) * FHH + gy) * FWW + gx];
            flds[c][y][x] = v;
        }
        __syncthreads();

        const float* wq = wT + (size_t)(cbase + c0) * 432 + q * 12;
        for (int c = 0; c < 16; ++c) {
            float f[4][3];
#pragma unroll
            for (int r = 0; r < 4; ++r)
#pragma unroll
                for (int k = 0; k < 3; ++k)
                    f[r][k] = flds[c][ry0 + r][rx0 + k];
#pragma unroll
            for (int tap = 0; tap < 9; ++tap) {
                int dy = tap / 3, dx = tap % 3;
                const float* wp = wq + (c * 9 + tap) * 48;
                float w[12];
#pragma unroll
                for (int o = 0; o < 12; ++o) w[o] = wp[o];
#pragma unroll
                for (int py = 0; py < 2; ++py) {
                    float fv = f[py + dy][dx];
#pragma unroll
                    for (int o = 0; o < 12; ++o)
                        acc[py][o] += fv * w[o];
                }
            }
        }
    }

    float* pout = partial + ((size_t)kg * NB + b) * OCP * NPOS;
#pragma unroll
    for (int o = 0; o < 12; ++o) {
        int oo = q * 12 + o;
        if (oo >= OC_TOTAL) continue;
        float* op = pout + (size_t)oo * NPOS;
#pragma unroll
        for (int py = 0; py < 2; ++py) {
            int pos = (ty0 + ry0 + py) * FWW + (tx0 + rx0);
            op[pos] = acc[py][o];
        }
    }
}

// ---------------- Decode (fused reduce) + bucket compact ----------------
__global__ __launch_bounds__(256) void decode_kernel(
    const float* __restrict__ partial,    // [nkg][4][48][4096]
    const float* __restrict__ anchors,
    const int* __restrict__ stridep,
    float* __restrict__ boxes,
    float* __restrict__ scores,
    int* __restrict__ gcnt,               // [NB][16] per-bucket counts
    u64* __restrict__ bucketbuf,          // [NB][16][CAP]
    int nkg)
{
    __shared__ int bcnt[NTH];
    __shared__ int gbs[NTH];
    if (threadIdx.x < NTH) bcnt[threadIdx.x] = 0;
    __syncthreads();

    int t = blockIdx.x * 256 + threadIdx.x;   // NB*9*4096
    int pos = t & (NPOS - 1);
    int ba = t >> 12;            // block-uniform
    int b = ba / 9;
    int a = ba - b * 9;

    float cls = 0.f, l0 = 0.f, l1 = 0.f, l2 = 0.f, l3 = 0.f;
    for (int kg = 0; kg < nkg; ++kg) {
        const float* pk = partial + ((size_t)kg * NB + b) * OCP * NPOS;
        cls += pk[(size_t)a * NPOS + pos];
        l0 += pk[(size_t)(NA + a * 4 + 0) * NPOS + pos];
        l1 += pk[(size_t)(NA + a * 4 + 1) * NPOS + pos];
        l2 += pk[(size_t)(NA + a * 4 + 2) * NPOS + pos];
        l3 += pk[(size_t)(NA + a * 4 + 3) * NPOS + pos];
    }

    float sig = 1.f / (1.f + expf(-cls));
    int n = pos * NA + a;
    const float* an = anchors + (size_t)n * 4;
    float ax1 = an[0], ay1 = an[1], ax2 = an[2], ay2 = an[3];
    float aw = ax2 - ax1, ah = ay2 - ay1;
    float acx = ax1 + 0.5f * aw, acy = ay1 + 0.5f * ah;
    float cx = acx + l0 * aw;
    float cy = acy + l1 * ah;
    float w = aw * expf(l2);
    float h = ah * expf(l3);
    float x1 = fminf(fmaxf(cx - 0.5f * w, 0.f), 512.f);
    float y1 = fminf(fmaxf(cy - 0.5f * h, 0.f), 512.f);
    float x2 = fminf(fmaxf(cx + 0.5f * w, 0.f), 512.f);
    float y2 = fminf(fmaxf(cy + 0.5f * h, 0.f), 512.f);
    int stride = stridep[0];
    float msz = 2.f * (float)stride;
    bool valid = (sig > 0.5f) && ((x2 - x1) >= msz) && ((y2 - y1) >= msz);
    ((float4*)boxes)[(size_t)b * NANCH + n] = make_float4(x1, y1, x2, y2);
    scores[(size_t)b * NANCH + n] = valid ? sig : -1.0f;

    // bucket index = first i with sig >= TH[i]
    int ib = -1, rloc = 0;
    if (valid) {
#pragma unroll
        for (int i = 0; i < NTH; ++i) {
            if (sig >= TH_LADDER[i]) { ib = i; break; }
        }
        rloc = atomicAdd(&bcnt[ib], 1);
    }
    __syncthreads();
    if (threadIdx.x < NTH)
        gbs[threadIdx.x] = bcnt[threadIdx.x]
            ? atomicAdd(&gcnt[b * NTH + threadIdx.x], bcnt[threadIdx.x]) : 0;
    __syncthreads();
    if (valid) {
        int slot = gbs[ib] + rloc;
        if (slot < CAP)
            bucketbuf[((size_t)b * NTH + ib) * CAP + slot] =
                ((u64)__float_as_uint(sig) << 32) | (unsigned int)(~n);
    }
}

// helper to write final outputs for one batch (lane i < 32)
__device__ __forceinline__ void write_outputs(
    int b, int i, bool okv, int idx, float sc,
    const float4* Bb4, const int* stridep,
    float* d_out, int* ifb, int* iok)
{
    float4 bb = Bb4[idx];
    float* eb = d_out + ((size_t)b * MAXROIS + i) * 5;
    eb[0] = okv ? bb.x : 0.f;
    eb[1] = okv ? bb.y : 0.f;
    eb[2] = okv ? bb.z : 0.f;
    eb[3] = okv ? bb.w : 0.f;
    eb[4] = okv ? sc : 0.f;
    d_out[NB * MAXROIS * 5 + b * MAXROIS + i] = okv ? 1.f : 0.f;
    int st = stridep[0];
    int fx1 = min(max(((int)bb.x) / st, 0), FWW - 1);
    int fy1 = min(max(((int)bb.y) / st, 0), FHH - 1);
    int fx2 = min(max(((int)bb.z) / st, fx1 + 1), FWW);
    int fy2 = min(max(((int)bb.w) / st, fy1 + 1), FHH);
    int r = b * MAXROIS + i;
    ifb[r * 4 + 0] = fx1;
    ifb[r * 4 + 1] = fy1;
    ifb[r * 4 + 2] = fx2;
    ifb[r * 4 + 3] = fy2;
    iok[r] = okv ? 1 : 0;
}

// ---------------- Fused sort + scan: bucket gather + bitonic + IOU mask scan ----------------
__global__ __launch_bounds__(512) void nms_sortscan_kernel(
    const u64* __restrict__ bucketbuf,
    const float* __restrict__ boxes,
    const int* __restrict__ gcnt,
    const int* __restrict__ stridep,
    float* __restrict__ d_out,
    int* __restrict__ ifb, int* __restrict__ iok, int* __restrict__ flag)
{
    __shared__ u64 skey[CAP];
    __shared__ float4 box_l[CAP];
    __shared__ u64 mask[CAP / 64];
    __shared__ int picks[MAXROIS];
    __shared__ int np_sh;

    int b = blockIdx.x;
    int tid = threadIdx.x;
    int lane = tid & 63;
    if (tid == 0) np_sh = 0;

    int isel, C, V, frc;
    pick_threshold2(gcnt, b, CAP, &isel, &C, &V, &frc);

    // gather buckets 0..isel into skey
    int off = 0;
    for (int i = 0; i <= isel; ++i) {
        int ci = gcnt[b * NTH + i];
        if (ci > CAP) ci = CAP;
        for (int j = tid; j < ci; j += 512)
            skey[off + j] = bucketbuf[((size_t)b * NTH + i) * CAP + j];
        off += ci;
        if (off >= CAP) break;
    }

    int CSZ = 64;
    while (CSZ < C) CSZ <<= 1;   // <= 1024
    for (int j = C + tid; j < CSZ; j += 512) skey[j] = 0ULL;

    int prev_cross = 1;
    for (int kk = 2; kk <= CSZ; kk <<= 1) {
        for (int jj = kk >> 1; jj > 0; jj >>= 1) {
            int cross = (jj >= 128) ? 1 : 0;
            if (cross || prev_cross) __syncthreads();
            for (int tt = tid; tt < (CSZ >> 1); tt += 512) {
                int i = ((tt & ~(jj - 1)) << 1) | (tt & (jj - 1));
                int l = i + jj;
                u64 a = skey[i], c2 = skey[l];
                bool up = ((i & kk) == 0);
                bool sw = up ? (a < c2) : (a > c2);
                if (sw) { skey[i] = c2; skey[l] = a; }
            }
            prev_cross = cross;
        }
    }
    __syncthreads();

    const float4* Bb4 = (const float4*)(boxes + (size_t)b * NANCH * 4);
    for (int j = tid; j < C; j += 512) {
        int id = (int)(~((unsigned int)(skey[j] & 0xFFFFFFFFULL)));
        box_l[j] = Bb4[id];
    }
    if (tid < CAP / 64) {
        int base = tid * 64;
        u64 m0;
        if (base >= C) m0 = ~0ULL;
        else if (base + 64 > C) m0 = ~((1ULL << (C - base)) - 1ULL);
        else m0 = 0ULL;
        mask[tid] = m0;
    }
    __syncthreads();

    for (int round = 0; round < MAXROIS; ++round) {
        u64 mw = (lane < CAP / 64) ? mask[lane] : ~0ULL;
        int bpos = __ffsll((u64)(~mw));
        int cand = bpos ? lane * 64 + bpos - 1 : 0x7FFFFFFF;
#pragma unroll
        for (int off2 = 32; off2 >= 1; off2 >>= 1)
            cand = min(cand, __shfl_xor(cand, off2));
        int pj = cand;
        if (pj == 0x7FFFFFFF) break;
        if (tid == 0) {
            picks[round] = pj;
            np_sh = round + 1;
            atomicOr(&mask[pj >> 6], 1ULL << (pj & 63));
        }
        float4 pb = box_l[pj];
        float parea = (pb.z - pb.x) * (pb.w - pb.y);
        int j0 = tid * 2;
        u64 curm = mask[tid >> 5];
        u64 addm = 0ULL;
#pragma unroll
        for (int d = 0; d < 2; ++d) {
            int j = j0 + d;
            if (j > pj && j < C && !((curm >> (j & 63)) & 1ULL)) {
                float4 bb2 = box_l[j];
                float xx1 = fmaxf(pb.x, bb2.x), yy1 = fmaxf(pb.y, bb2.y);
                float xx2 = fminf(pb.z, bb2.z), yy2 = fminf(pb.w, bb2.w);
                float inter = fmaxf(xx2 - xx1, 0.f) * fmaxf(yy2 - yy1, 0.f);
                float a2 = (bb2.z - bb2.x) * (bb2.w - bb2.y);
                float iou = inter / (parea + a2 - inter + 1e-9f);
                if (iou > 0.3f) addm |= 1ULL << (j & 63);
            }
        }
        if (addm) atomicOr(&mask[tid >> 5], addm);
        __syncthreads();
    }
    __syncthreads();

    int np = np_sh;
    bool need_fb = frc || (np < MAXROIS && V > C);
    if (tid == 0) flag[b] = need_fb ? 1 : 0;
    if (!need_fb && tid < MAXROIS) {
        int i = tid;
        bool okv = i < np;
        int slot = okv ? picks[i] : 0;
        u64 k = skey[slot];
        int idx = okv ? (int)(~((unsigned int)(k & 0xFFFFFFFFULL))) : 0;
        float sc = okv ? __uint_as_float((unsigned int)(k >> 32)) : 0.f;
        write_outputs(b, i, okv, idx, sc, Bb4, stridep, d_out, ifb, iok);
    }
}

// ---------------- NMS fallback: pop loop, runs only if flag[b] ----------------
__global__ __launch_bounds__(1024) void nms_fallback_kernel(
    const float* __restrict__ boxes,
    const float* __restrict__ scores,
    const int* __restrict__ stridep,
    float* __restrict__ d_out,
    int* __restrict__ ifb,
    int* __restrict__ iok,
    const int* __restrict__ flag)
{
    __shared__ float s[NANCH];
    __shared__ float2 cmax[NCHUNK];
    __shared__ int   picks_sh[MAXROIS];
    __shared__ float pscore_sh[MAXROIS];

    int b = blockIdx.x;
    if (flag[b] == 0) return;

    const float4* Bb4 = (const float4*)(boxes + (size_t)b * NANCH * 4);
    const float* Sb = scores + (size_t)b * NANCH;
    int lane = threadIdx.x & 63;
    int w = threadIdx.x >> 6;

    for (int k = 0; k < 36; ++k) {
        int ch = w * 36 + k;
        int j = ch * 64 + lane;
        float v = Sb[j];
        s[j] = v;
        float bv = v; int bi = j;
#pragma unroll
        for (int off = 32; off >= 1; off >>= 1) {
            float ov = __shfl_xor(bv, off);
            int   oi = __shfl_xor(bi, off);
            if (ov > bv || (ov == bv && oi < bi)) { bv = ov; bi = oi; }
        }
        if (lane == 0) cmax[ch] = make_float2(bv, __int_as_float(bi));
    }
    __syncthreads();
    if (w != 0) return;

    float px1 = 0.f, py1 = 0.f, px2 = 0.f, py2 = 0.f, parea = 0.f;
    int np = 0;
    while (np < MAXROIS) {
        float bv = -2.f; int bi = 0x7fffffff;
#pragma unroll
        for (int k = 0; k < 9; ++k) {
            float2 cm = cmax[lane * 9 + k];
            int ci = __float_as_int(cm.y);
            if (cm.x > bv || (cm.x == bv && ci < bi)) { bv = cm.x; bi = ci; }
        }
#pragma unroll
        for (int off = 32; off >= 1; off >>= 1) {
            float ov = __shfl_xor(bv, off);
            int   oi = __shfl_xor(bi, off);
            if (ov > bv || (ov == bv && oi < bi)) { bv = ov; bi = oi; }
        }
        if (bv <= 0.f) break;
        int fi = bi; float fs = bv;

        float4 cbb = Bb4[fi];

        bool sup = false;
        if (lane < np) {
            float xx1 = fmaxf(px1, cbb.x), yy1 = fmaxf(py1, cbb.y);
            float xx2 = fminf(px2, cbb.z), yy2 = fminf(py2, cbb.w);
            float inter = fmaxf(xx2 - xx1, 0.f) * fmaxf(yy2 - yy1, 0.f);
            float a2 = (cbb.z - cbb.x) * (cbb.w - cbb.y);
            float iou = inter / (parea + a2 - inter + 1e-9f);
            sup = iou > 0.3f;
        }
        u64 m = __ballot(sup);

        int ch = fi >> 6;
        int j = ch * 64 + lane;
        float sv = (j == fi) ? -1.f : s[j];
        if (j == fi) s[j] = -1.f;
        float nv = sv; int ni = j;
#pragma unroll
        for (int off = 32; off >= 1; off >>= 1) {
            float ov = __shfl_xor(nv, off);
            int   oi = __shfl_xor(ni, off);
            if (ov > nv || (ov == nv && oi < ni)) { nv = ov; ni = oi; }
        }
        if (lane == 0) cmax[ch] = make_float2(nv, __int_as_float(ni));

        if (m == 0ULL) {
            if (lane == np) {
                px1 = cbb.x; py1 = cbb.y; px2 = cbb.z; py2 = cbb.w;
                parea = (px2 - px1) * (py2 - py1);
            }
            picks_sh[np] = fi;
            pscore_sh[np] = fs;
            ++np;
        }
    }

    if (lane < MAXROIS) {
        int i = lane;
        bool okv = i < np;
        int idx = okv ? picks_sh[i] : 0;
        float sc = okv ? pscore_sh[i] : 0.f;
        write_outputs(b, i, okv, idx, sc, Bb4, stridep, d_out, ifb, iok);
    }
}

// ---------------- ROI v3: block per (b,c); plane staged in LDS once ----------------
__global__ __launch_bounds__(256) void roi_kernel(
    const float* __restrict__ feat,   // [4,256,64,64]
    const int* __restrict__ ifb,      // [128][4]
    const int* __restrict__ iok,      // [128]
    float* __restrict__ out_rois)     // [128,256,7,7]
{
    __shared__ float plane[NPOS];        // 16 KB
    __shared__ int sifb[MAXROIS * 4];
    __shared__ int siok[MAXROIS];

    int bc = blockIdx.x;     // b*256 + c
    int b = bc >> 8;
    int c = bc & 255;

    const float4* F4 = (const float4*)(feat + (size_t)bc * NPOS);
    float4* P4 = (float4*)plane;
    for (int i = threadIdx.x; i < NPOS / 4; i += 256)
        P4[i] = F4[i];
    if (threadIdx.x < MAXROIS * 4) sifb[threadIdx.x] = ifb[b * MAXROIS * 4 + threadIdx.x];
    if (threadIdx.x < MAXROIS) siok[threadIdx.x] = iok[b * MAXROIS + threadIdx.x];
    __syncthreads();

    for (int t = threadIdx.x; t < MAXROIS * 49; t += 256) {
        int r = t / 49;
        int bin = t - r * 49;
        int i = bin / 7;
        int j = bin - i * 7;
        float outv = 0.f;
        if (siok[r]) {
            int x1 = sifb[r * 4 + 0];
            int y1 = sifb[r * 4 + 1];
            int x2 = sifb[r * 4 + 2];
            int y2 = sifb[r * 4 + 3];
            int h = y2 - y1;
            int w = x2 - x1;
            int rs = y1 + (i * h) / ROI;
            int re = y1 + ((i + 1) * h + ROI - 1) / ROI;
            int cs = x1 + (j * w) / ROI;
            int ce = x1 + ((j + 1) * w + ROI - 1) / ROI;
            float m = NEGV;
            for (int y = rs; y < re; ++y) {
                const float* row = plane + y * FWW;
                for (int x = cs; x < ce; ++x) m = fmaxf(m, row[x]);
            }
            outv = m;
        }
        out_rois[((size_t)(b * MAXROIS + r) * CIN + c) * 49 + bin] = outv;
    }
}

extern "C" void kernel_launch(void* const* d_in, const int* in_sizes, int n_in,
                              void* d_out, int out_size, void* d_ws, size_t ws_size,
                              hipStream_t stream) {
    const float* feat    = (const float*)d_in[0];
    const float* anchors = (const float*)d_in[1];
    const float* wcls    = (const float*)d_in[2];
    const float* wloc    = (const float*)d_in[3];
    const int*   stridep = (const int*)d_in[4];
    float* out = (float*)d_out;
    float* ws  = (float*)d_ws;

    const size_t P1 = (size_t)NB * OCP * NPOS;        // 786432 floats per kg
    const size_t WTN = 256 * 9 * 48;                  // 110592 floats
    const size_t BKT = (size_t)NB * NTH * CAP * 2;    // bucketbuf (u64) in floats

    auto need = [&](int nk) -> size_t {
        size_t f = P1 * nk
                 + 589824 + 147456 + WTN
                 + BKT
                 + 2048;
        return f * 4;
    };
    int nkg = 16;
    if (ws_size < need(16)) {
        if (ws_size >= need(8)) { nkg = 8; }
        else { nkg = 4; }
    }

    float* partial   = ws;
    float* boxes     = partial + P1 * nkg;
    float* scores    = boxes + (size_t)NB * NANCH * 4;
    float* wT        = scores + (size_t)NB * NANCH;
    u64*   bucketbuf = (u64*)(wT + WTN);
    float* tailf     = (float*)(bucketbuf + (size_t)NB * NTH * CAP);
    int*   ifb       = (int*)tailf;          // 512
    int*   iok       = ifb + 512;            // 128
    int*   flag      = iok + 128;            // 4
    int*   gcnt      = flag + 4;             // 64

    wtrans_kernel<<<432, 256, 0, stream>>>(wcls, wloc, wT, gcnt);
    conv_kernel<<<128 * nkg, 256, 0, stream>>>(feat, wT, partial, nkg, CIN / nkg);
    decode_kernel<<<(NB * NANCH) / 256, 256, 0, stream>>>(partial, anchors, stridep, boxes, scores, gcnt, bucketbuf, nkg);
    nms_sortscan_kernel<<<NB, 512, 0, stream>>>(bucketbuf, boxes, gcnt, stridep, out, ifb, iok, flag);
    nms_fallback_kernel<<<NB, 1024, 0, stream>>>(boxes, scores, stridep, out, ifb, iok, flag);
    roi_kernel<<<NB * CIN, 256, 0, stream>>>(feat, ifb, iok, out + NB * MAXROIS * 5 + NB * MAXROIS);
}

// Round 21
// 131.523 us; speedup vs baseline: 1.0474x; 1.0474x over previous
//
#include <hip/hip_runtime.h>
#include <hip/hip_bf16.h>

#define FHH 64
#define FWW 64
#define CIN 256
#define NB 4
#define NA 9
#define NANCH 36864
#define NPOS 4096
#define OC_TOTAL 45
#define OCP 48
#define MAXROIS 32
#define ROI 7
#define NEGV -1e30f
#define NCHUNK 576
#define NTH 16
#define CAP 1024

typedef unsigned long long u64;

__device__ __constant__ const float TH_LADDER[NTH] = {
    0.9999f, 0.9998f, 0.9995f, 0.999f, 0.998f, 0.997f, 0.995f, 0.993f,
    0.99f, 0.987f, 0.984f, 0.98f, 0.975f, 0.97f, 0.96f, 0.0f};

// choose deepest ladder index with cumulative count <= cap (gcnt = per-bucket counts)
__device__ __forceinline__ void pick_threshold2(
    const int* __restrict__ gcnt, int b, int cap,
    int* isel, int* C, int* V, int* frc)
{
    int cum = 0, bestC = 0, best_i = -1;
#pragma unroll
    for (int i = 0; i < NTH; ++i) {
        cum += gcnt[b * NTH + i];
        if (cum <= cap && cum > bestC) { bestC = cum; best_i = i; }
    }
    int f = (gcnt[b * NTH + 0] > cap) ? 1 : 0;
    if (f) { bestC = cap; best_i = 0; }
    *isel = best_i; *C = bestC; *V = cum; *frc = f;
}

// ---------------- Weight transpose + gcnt zero: wT[256][9][48] ----------------
__global__ __launch_bounds__(256) void wtrans_kernel(
    const float* __restrict__ wcls,
    const float* __restrict__ wloc,
    float* __restrict__ wT,
    int* __restrict__ gcnt)
{
    if (blockIdx.x == 0 && threadIdx.x < NB * NTH) gcnt[threadIdx.x] = 0;
    int idx = blockIdx.x * 256 + threadIdx.x;   // 110592 = 256*9*48
    int o = idx % 48;
    int rest = idx / 48;
    int tap = rest % 9;
    int c = rest / 9;
    float v = 0.f;
    if (o < OC_TOTAL) {
        v = (o < NA) ? wcls[((size_t)o * CIN + c) * 9 + tap]
                     : wloc[((size_t)(o - NA) * CIN + c) * 9 + tap];
    }
    wT[idx] = v;
}

// ---------------- Conv v8 (R18): weights via scalar pipe, features in LDS ----------------
// grid: 64 units x nkg = 1024 blocks, 256 threads; LDS 23KB. Measured ~59us.
__global__ __launch_bounds__(256) void conv_kernel(
    const float* __restrict__ feat,
    const float* __restrict__ wT,      // [256][9][48]
    float* __restrict__ partial,       // [nkg][4][48][4096]
    int nkg, int cpk)
{
    __shared__ float flds[16][18][20];   // 23040 B

    int blk = blockIdx.x;
    int low = blk & 7;
    int rest = blk >> 3;
    int kg = rest % nkg;
    int uhi = rest / nkg;
    int unit = uhi * 8 + low;
    int b = unit >> 4;
    int tile = unit & 15;

    int ty0 = (tile >> 2) * 16;
    int tx0 = (tile & 3) * 16;

    int pb = threadIdx.x & 63;
    int q = __builtin_amdgcn_readfirstlane(threadIdx.x >> 6);
    int ry0 = (pb >> 3) * 2;
    int rx0 = (pb & 7) * 2;

    int cbase = kg * cpk;

    float acc[2][2][12];
#pragma unroll
    for (int py = 0; py < 2; ++py)
#pragma unroll
        for (int px = 0; px < 2; ++px)
#pragma unroll
            for (int o = 0; o < 12; ++o) acc[py][px][o] = 0.f;

    for (int c0 = 0; c0 < cpk; c0 += 16) {
        __syncthreads();
        for (int idx = threadIdx.x; idx < 16 * 324; idx += 256) {
            int c = idx / 324;
            int r = idx - c * 324;
            int y = r / 18;
            int x = r - y * 18;
            int gy = ty0 + y - 1;
            int gx = tx0 + x - 1;
            float v = 0.f;
            if ((unsigned)gy < FHH && (unsigned)gx < FWW)
                v = feat[((size_t)(b * CIN + cbase + c0 + c) * FHH + gy) * FWW + gx];
            flds[c][y][x] = v;
        }
        __syncthreads();

        const float* wq = wT + (size_t)(cbase + c0) * 432 + q * 12;
        for (int c = 0; c < 16; ++c) {
            float f[4][4];
#pragma unroll
            for (int r = 0; r < 4; ++r) {
                float2 a0 = *(const float2*)&flds[c][ry0 + r][rx0];
                float2 a1 = *(const float2*)&flds[c][ry0 + r][rx0 + 2];
                f[r][0] = a0.x; f[r][1] = a0.y; f[r][2] = a1.x; f[r][3] = a1.y;
            }
#pragma unroll
            for (int tap = 0; tap < 9; ++tap) {
                int dy = tap / 3, dx = tap % 3;
                const float* wp = wq + (c * 9 + tap) * 48;
                float w[12];
#pragma unroll
                for (int o = 0; o < 12; ++o) w[o] = wp[o];
#pragma unroll
                for (int py = 0; py < 2; ++py)
#pragma unroll
                for (int px = 0; px < 2; ++px) {
                    float fv = f[py + dy][px + dx];
#pragma unroll
                    for (int o = 0; o < 12; ++o)
                        acc[py][px][o] += fv * w[o];
                }
            }
        }
    }

    float* pout = partial + ((size_t)kg * NB + b) * OCP * NPOS;
#pragma unroll
    for (int o = 0; o < 12; ++o) {
        int oo = q * 12 + o;
        if (oo >= OC_TOTAL) continue;    // skip 3 dead padding planes
        float* op = pout + (size_t)oo * NPOS;
#pragma unroll
        for (int py = 0; py < 2; ++py)
#pragma unroll
        for (int px = 0; px < 2; ++px) {
            int pos = (ty0 + ry0 + py) * FWW + (tx0 + rx0 + px);
            op[pos] = acc[py][px][o];
        }
    }
}

// ---------------- Decode (fused reduce) + bucket compact ----------------
__global__ __launch_bounds__(256) void decode_kernel(
    const float* __restrict__ partial,    // [nkg][4][48][4096]
    const float* __restrict__ anchors,
    const int* __restrict__ stridep,
    float* __restrict__ boxes,
    float* __restrict__ scores,
    int* __restrict__ gcnt,               // [NB][16] per-bucket counts
    u64* __restrict__ bucketbuf,          // [NB][16][CAP]
    int nkg)
{
    __shared__ int bcnt[NTH];
    __shared__ int gbs[NTH];
    if (threadIdx.x < NTH) bcnt[threadIdx.x] = 0;
    __syncthreads();

    int t = blockIdx.x * 256 + threadIdx.x;   // NB*9*4096
    int pos = t & (NPOS - 1);
    int ba = t >> 12;            // block-uniform
    int b = ba / 9;
    int a = ba - b * 9;

    float cls = 0.f, l0 = 0.f, l1 = 0.f, l2 = 0.f, l3 = 0.f;
    for (int kg = 0; kg < nkg; ++kg) {
        const float* pk = partial + ((size_t)kg * NB + b) * OCP * NPOS;
        cls += pk[(size_t)a * NPOS + pos];
        l0 += pk[(size_t)(NA + a * 4 + 0) * NPOS + pos];
        l1 += pk[(size_t)(NA + a * 4 + 1) * NPOS + pos];
        l2 += pk[(size_t)(NA + a * 4 + 2) * NPOS + pos];
        l3 += pk[(size_t)(NA + a * 4 + 3) * NPOS + pos];
    }

    float sig = 1.f / (1.f + expf(-cls));
    int n = pos * NA + a;
    const float* an = anchors + (size_t)n * 4;
    float ax1 = an[0], ay1 = an[1], ax2 = an[2], ay2 = an[3];
    float aw = ax2 - ax1, ah = ay2 - ay1;
    float acx = ax1 + 0.5f * aw, acy = ay1 + 0.5f * ah;
    float cx = acx + l0 * aw;
    float cy = acy + l1 * ah;
    float w = aw * expf(l2);
    float h = ah * expf(l3);
    float x1 = fminf(fmaxf(cx - 0.5f * w, 0.f), 512.f);
    float y1 = fminf(fmaxf(cy - 0.5f * h, 0.f), 512.f);
    float x2 = fminf(fmaxf(cx + 0.5f * w, 0.f), 512.f);
    float y2 = fminf(fmaxf(cy + 0.5f * h, 0.f), 512.f);
    int stride = stridep[0];
    float msz = 2.f * (float)stride;
    bool valid = (sig > 0.5f) && ((x2 - x1) >= msz) && ((y2 - y1) >= msz);
    ((float4*)boxes)[(size_t)b * NANCH + n] = make_float4(x1, y1, x2, y2);
    scores[(size_t)b * NANCH + n] = valid ? sig : -1.0f;

    // bucket index = first i with sig >= TH[i]
    int ib = -1, rloc = 0;
    if (valid) {
#pragma unroll
        for (int i = 0; i < NTH; ++i) {
            if (sig >= TH_LADDER[i]) { ib = i; break; }
        }
        rloc = atomicAdd(&bcnt[ib], 1);
    }
    __syncthreads();
    if (threadIdx.x < NTH)
        gbs[threadIdx.x] = bcnt[threadIdx.x]
            ? atomicAdd(&gcnt[b * NTH + threadIdx.x], bcnt[threadIdx.x]) : 0;
    __syncthreads();
    if (valid) {
        int slot = gbs[ib] + rloc;
        if (slot < CAP)
            bucketbuf[((size_t)b * NTH + ib) * CAP + slot] =
                ((u64)__float_as_uint(sig) << 32) | (unsigned int)(~n);
    }
}

// helper to write final outputs for one batch (lane i < 32)
__device__ __forceinline__ void write_outputs(
    int b, int i, bool okv, int idx, float sc,
    const float4* Bb4, const int* stridep,
    float* d_out, int* ifb, int* iok)
{
    float4 bb = Bb4[idx];
    float* eb = d_out + ((size_t)b * MAXROIS + i) * 5;
    eb[0] = okv ? bb.x : 0.f;
    eb[1] = okv ? bb.y : 0.f;
    eb[2] = okv ? bb.z : 0.f;
    eb[3] = okv ? bb.w : 0.f;
    eb[4] = okv ? sc : 0.f;
    d_out[NB * MAXROIS * 5 + b * MAXROIS + i] = okv ? 1.f : 0.f;
    int st = stridep[0];
    int fx1 = min(max(((int)bb.x) / st, 0), FWW - 1);
    int fy1 = min(max(((int)bb.y) / st, 0), FHH - 1);
    int fx2 = min(max(((int)bb.z) / st, fx1 + 1), FWW);
    int fy2 = min(max(((int)bb.w) / st, fy1 + 1), FHH);
    int r = b * MAXROIS + i;
    ifb[r * 4 + 0] = fx1;
    ifb[r * 4 + 1] = fy1;
    ifb[r * 4 + 2] = fx2;
    ifb[r * 4 + 3] = fy2;
    iok[r] = okv ? 1 : 0;
}

// ---------------- Fused sort + scan: bucket gather + bitonic + IOU mask scan ----------------
__global__ __launch_bounds__(512) void nms_sortscan_kernel(
    const u64* __restrict__ bucketbuf,
    const float* __restrict__ boxes,
    const int* __restrict__ gcnt,
    const int* __restrict__ stridep,
    float* __restrict__ d_out,
    int* __restrict__ ifb, int* __restrict__ iok, int* __restrict__ flag)
{
    __shared__ u64 skey[CAP];
    __shared__ float4 box_l[CAP];
    __shared__ u64 mask[CAP / 64];
    __shared__ int picks[MAXROIS];
    __shared__ int np_sh;

    int b = blockIdx.x;
    int tid = threadIdx.x;
    int lane = tid & 63;
    if (tid == 0) np_sh = 0;

    int isel, C, V, frc;
    pick_threshold2(gcnt, b, CAP, &isel, &C, &V, &frc);

    // gather buckets 0..isel into skey
    int off = 0;
    for (int i = 0; i <= isel; ++i) {
        int ci = gcnt[b * NTH + i];
        if (ci > CAP) ci = CAP;
        for (int j = tid; j < ci; j += 512)
            skey[off + j] = bucketbuf[((size_t)b * NTH + i) * CAP + j];
        off += ci;
        if (off >= CAP) break;
    }

    int CSZ = 64;
    while (CSZ < C) CSZ <<= 1;   // <= 1024
    for (int j = C + tid; j < CSZ; j += 512) skey[j] = 0ULL;

    int prev_cross = 1;
    for (int kk = 2; kk <= CSZ; kk <<= 1) {
        for (int jj = kk >> 1; jj > 0; jj >>= 1) {
            int cross = (jj >= 128) ? 1 : 0;
            if (cross || prev_cross) __syncthreads();
            for (int tt = tid; tt < (CSZ >> 1); tt += 512) {
                int i = ((tt & ~(jj - 1)) << 1) | (tt & (jj - 1));
                int l = i + jj;
                u64 a = skey[i], c2 = skey[l];
                bool up = ((i & kk) == 0);
                bool sw = up ? (a < c2) : (a > c2);
                if (sw) { skey[i] = c2; skey[l] = a; }
            }
            prev_cross = cross;
        }
    }
    __syncthreads();

    const float4* Bb4 = (const float4*)(boxes + (size_t)b * NANCH * 4);
    for (int j = tid; j < C; j += 512) {
        int id = (int)(~((unsigned int)(skey[j] & 0xFFFFFFFFULL)));
        box_l[j] = Bb4[id];
    }
    if (tid < CAP / 64) {
        int base = tid * 64;
        u64 m0;
        if (base >= C) m0 = ~0ULL;
        else if (base + 64 > C) m0 = ~((1ULL << (C - base)) - 1ULL);
        else m0 = 0ULL;
        mask[tid] = m0;
    }
    __syncthreads();

    for (int round = 0; round < MAXROIS; ++round) {
        u64 mw = (lane < CAP / 64) ? mask[lane] : ~0ULL;
        int bpos = __ffsll((u64)(~mw));
        int cand = bpos ? lane * 64 + bpos - 1 : 0x7FFFFFFF;
#pragma unroll
        for (int off2 = 32; off2 >= 1; off2 >>= 1)
            cand = min(cand, __shfl_xor(cand, off2));
        int pj = cand;
        if (pj == 0x7FFFFFFF) break;
        if (tid == 0) {
            picks[round] = pj;
            np_sh = round + 1;
            atomicOr(&mask[pj >> 6], 1ULL << (pj & 63));
        }
        float4 pb = box_l[pj];
        float parea = (pb.z - pb.x) * (pb.w - pb.y);
        int j0 = tid * 2;
        u64 curm = mask[tid >> 5];
        u64 addm = 0ULL;
#pragma unroll
        for (int d = 0; d < 2; ++d) {
            int j = j0 + d;
            if (j > pj && j < C && !((curm >> (j & 63)) & 1ULL)) {
                float4 bb2 = box_l[j];
                float xx1 = fmaxf(pb.x, bb2.x), yy1 = fmaxf(pb.y, bb2.y);
                float xx2 = fminf(pb.z, bb2.z), yy2 = fminf(pb.w, bb2.w);
                float inter = fmaxf(xx2 - xx1, 0.f) * fmaxf(yy2 - yy1, 0.f);
                float a2 = (bb2.z - bb2.x) * (bb2.w - bb2.y);
                float iou = inter / (parea + a2 - inter + 1e-9f);
                if (iou > 0.3f) addm |= 1ULL << (j & 63);
            }
        }
        if (addm) atomicOr(&mask[tid >> 5], addm);
        __syncthreads();
    }
    __syncthreads();

    int np = np_sh;
    bool need_fb = frc || (np < MAXROIS && V > C);
    if (tid == 0) flag[b] = need_fb ? 1 : 0;
    if (!need_fb && tid < MAXROIS) {
        int i = tid;
        bool okv = i < np;
        int slot = okv ? picks[i] : 0;
        u64 k = skey[slot];
        int idx = okv ? (int)(~((unsigned int)(k & 0xFFFFFFFFULL))) : 0;
        float sc = okv ? __uint_as_float((unsigned int)(k >> 32)) : 0.f;
        write_outputs(b, i, okv, idx, sc, Bb4, stridep, d_out, ifb, iok);
    }
}

// ---------------- NMS fallback: pop loop, runs only if flag[b] ----------------
__global__ __launch_bounds__(1024) void nms_fallback_kernel(
    const float* __restrict__ boxes,
    const float* __restrict__ scores,
    const int* __restrict__ stridep,
    float* __restrict__ d_out,
    int* __restrict__ ifb,
    int* __restrict__ iok,
    const int* __restrict__ flag)
{
    __shared__ float s[NANCH];
    __shared__ float2 cmax[NCHUNK];
    __shared__ int   picks_sh[MAXROIS];
    __shared__ float pscore_sh[MAXROIS];

    int b = blockIdx.x;
    if (flag[b] == 0) return;

    const float4* Bb4 = (const float4*)(boxes + (size_t)b * NANCH * 4);
    const float* Sb = scores + (size_t)b * NANCH;
    int lane = threadIdx.x & 63;
    int w = threadIdx.x >> 6;

    for (int k = 0; k < 36; ++k) {
        int ch = w * 36 + k;
        int j = ch * 64 + lane;
        float v = Sb[j];
        s[j] = v;
        float bv = v; int bi = j;
#pragma unroll
        for (int off = 32; off >= 1; off >>= 1) {
            float ov = __shfl_xor(bv, off);
            int   oi = __shfl_xor(bi, off);
            if (ov > bv || (ov == bv && oi < bi)) { bv = ov; bi = oi; }
        }
        if (lane == 0) cmax[ch] = make_float2(bv, __int_as_float(bi));
    }
    __syncthreads();
    if (w != 0) return;

    float px1 = 0.f, py1 = 0.f, px2 = 0.f, py2 = 0.f, parea = 0.f;
    int np = 0;
    while (np < MAXROIS) {
        float bv = -2.f; int bi = 0x7fffffff;
#pragma unroll
        for (int k = 0; k < 9; ++k) {
            float2 cm = cmax[lane * 9 + k];
            int ci = __float_as_int(cm.y);
            if (cm.x > bv || (cm.x == bv && ci < bi)) { bv = cm.x; bi = ci; }
        }
#pragma unroll
        for (int off = 32; off >= 1; off >>= 1) {
            float ov = __shfl_xor(bv, off);
            int   oi = __shfl_xor(bi, off);
            if (ov > bv || (ov == bv && oi < bi)) { bv = ov; bi = oi; }
        }
        if (bv <= 0.f) break;
        int fi = bi; float fs = bv;

        float4 cbb = Bb4[fi];

        bool sup = false;
        if (lane < np) {
            float xx1 = fmaxf(px1, cbb.x), yy1 = fmaxf(py1, cbb.y);
            float xx2 = fminf(px2, cbb.z), yy2 = fminf(py2, cbb.w);
            float inter = fmaxf(xx2 - xx1, 0.f) * fmaxf(yy2 - yy1, 0.f);
            float a2 = (cbb.z - cbb.x) * (cbb.w - cbb.y);
            float iou = inter / (parea + a2 - inter + 1e-9f);
            sup = iou > 0.3f;
        }
        u64 m = __ballot(sup);

        int ch = fi >> 6;
        int j = ch * 64 + lane;
        float sv = (j == fi) ? -1.f : s[j];
        if (j == fi) s[j] = -1.f;
        float nv = sv; int ni = j;
#pragma unroll
        for (int off = 32; off >= 1; off >>= 1) {
            float ov = __shfl_xor(nv, off);
            int   oi = __shfl_xor(ni, off);
            if (ov > nv || (ov == nv && oi < ni)) { nv = ov; ni = oi; }
        }
        if (lane == 0) cmax[ch] = make_float2(nv, __int_as_float(ni));

        if (m == 0ULL) {
            if (lane == np) {
                px1 = cbb.x; py1 = cbb.y; px2 = cbb.z; py2 = cbb.w;
                parea = (px2 - px1) * (py2 - py1);
            }
            picks_sh[np] = fi;
            pscore_sh[np] = fs;
            ++np;
        }
    }

    if (lane < MAXROIS) {
        int i = lane;
        bool okv = i < np;
        int idx = okv ? picks_sh[i] : 0;
        float sc = okv ? pscore_sh[i] : 0.f;
        write_outputs(b, i, okv, idx, sc, Bb4, stridep, d_out, ifb, iok);
    }
}

// ---------------- ROI v3: block per (b,c); plane staged in LDS once ----------------
__global__ __launch_bounds__(256) void roi_kernel(
    const float* __restrict__ feat,   // [4,256,64,64]
    const int* __restrict__ ifb,      // [128][4]
    const int* __restrict__ iok,      // [128]
    float* __restrict__ out_rois)     // [128,256,7,7]
{
    __shared__ float plane[NPOS];        // 16 KB
    __shared__ int sifb[MAXROIS * 4];
    __shared__ int siok[MAXROIS];

    int bc = blockIdx.x;     // b*256 + c
    int b = bc >> 8;
    int c = bc & 255;

    const float4* F4 = (const float4*)(feat + (size_t)bc * NPOS);
    float4* P4 = (float4*)plane;
    for (int i = threadIdx.x; i < NPOS / 4; i += 256)
        P4[i] = F4[i];
    if (threadIdx.x < MAXROIS * 4) sifb[threadIdx.x] = ifb[b * MAXROIS * 4 + threadIdx.x];
    if (threadIdx.x < MAXROIS) siok[threadIdx.x] = iok[b * MAXROIS + threadIdx.x];
    __syncthreads();

    for (int t = threadIdx.x; t < MAXROIS * 49; t += 256) {
        int r = t / 49;
        int bin = t - r * 49;
        int i = bin / 7;
        int j = bin - i * 7;
        float outv = 0.f;
        if (siok[r]) {
            int x1 = sifb[r * 4 + 0];
            int y1 = sifb[r * 4 + 1];
            int x2 = sifb[r * 4 + 2];
            int y2 = sifb[r * 4 + 3];
            int h = y2 - y1;
            int w = x2 - x1;
            int rs = y1 + (i * h) / ROI;
            int re = y1 + ((i + 1) * h + ROI - 1) / ROI;
            int cs = x1 + (j * w) / ROI;
            int ce = x1 + ((j + 1) * w + ROI - 1) / ROI;
            float m = NEGV;
            for (int y = rs; y < re; ++y) {
                const float* row = plane + y * FWW;
                for (int x = cs; x < ce; ++x) m = fmaxf(m, row[x]);
            }
            outv = m;
        }
        out_rois[((size_t)(b * MAXROIS + r) * CIN + c) * 49 + bin] = outv;
    }
}

extern "C" void kernel_launch(void* const* d_in, const int* in_sizes, int n_in,
                              void* d_out, int out_size, void* d_ws, size_t ws_size,
                              hipStream_t stream) {
    const float* feat    = (const float*)d_in[0];
    const float* anchors = (const float*)d_in[1];
    const float* wcls    = (const float*)d_in[2];
    const float* wloc    = (const float*)d_in[3];
    const int*   stridep = (const int*)d_in[4];
    float* out = (float*)d_out;
    float* ws  = (float*)d_ws;

    const size_t P1 = (size_t)NB * OCP * NPOS;        // 786432 floats per kg
    const size_t WTN = 256 * 9 * 48;                  // 110592 floats
    const size_t BKT = (size_t)NB * NTH * CAP * 2;    // bucketbuf (u64) in floats

    auto need = [&](int nk) -> size_t {
        size_t f = P1 * nk
                 + 589824 + 147456 + WTN
                 + BKT
                 + 2048;
        return f * 4;
    };
    int nkg = 16;
    if (ws_size < need(16)) {
        if (ws_size >= need(8)) { nkg = 8; }
        else { nkg = 4; }
    }

    float* partial   = ws;
    float* boxes     = partial + P1 * nkg;
    float* scores    = boxes + (size_t)NB * NANCH * 4;
    float* wT        = scores + (size_t)NB * NANCH;
    u64*   bucketbuf = (u64*)(wT + WTN);
    float* tailf     = (float*)(bucketbuf + (size_t)NB * NTH * CAP);
    int*   ifb       = (int*)tailf;          // 512
    int*   iok       = ifb + 512;            // 128
    int*   flag      = iok + 128;            // 4
    int*   gcnt      = flag + 4;             // 64

    wtrans_kernel<<<432, 256, 0, stream>>>(wcls, wloc, wT, gcnt);
    conv_kernel<<<64 * nkg, 256, 0, stream>>>(feat, wT, partial, nkg, CIN / nkg);
    decode_kernel<<<(NB * NANCH) / 256, 256, 0, stream>>>(partial, anchors, stridep, boxes, scores, gcnt, bucketbuf, nkg);
    nms_sortscan_kernel<<<NB, 512, 0, stream>>>(bucketbuf, boxes, gcnt, stridep, out, ifb, iok, flag);
    nms_fallback_kernel<<<NB, 1024, 0, stream>>>(boxes, scores, stridep, out, ifb, iok, flag);
    roi_kernel<<<NB * CIN, 256, 0, stream>>>(feat, ifb, iok, out + NB * MAXROIS * 5 + NB * MAXROIS);
}